// Round 1
// baseline (810.722 us; speedup 1.0000x reference)
//
#include <hip/hip_runtime.h>

#define N_NODES 100000
#define N_EDGES 3200000
#define D_FEAT 256
#define HIDDEN 16
#define OUT 256
#define M3 32   // nodes per block in k_out

// Monotone float<->uint mapping so unsigned atomicMax == float max.
__device__ __forceinline__ unsigned enc_f32(float f) {
    unsigned u = __float_as_uint(f);
    return (u & 0x80000000u) ? ~u : (u | 0x80000000u);
}
__device__ __forceinline__ float dec_f32(unsigned u) {
    unsigned b = (u & 0x80000000u) ? (u & 0x7FFFFFFFu) : ~u;
    return __uint_as_float(b);
}

// Kernel 1: h_agg = x @ W_agg + b_agg  (and zero-init agg_enc).
// One thread per (node, k): 16 threads share a node's x row (L1 broadcast).
__global__ __launch_bounds__(256) void k_hagg(
    const float* __restrict__ x, const float* __restrict__ W_agg,
    const float* __restrict__ b_agg, float* __restrict__ h_agg,
    unsigned* __restrict__ agg_enc)
{
    __shared__ float Wl[D_FEAT * HIDDEN];   // 16 KB
    int t = threadIdx.x;
    for (int i = t; i < D_FEAT * HIDDEN; i += 256) Wl[i] = W_agg[i];
    __syncthreads();

    int gid = blockIdx.x * 256 + t;
    if (gid >= N_NODES * HIDDEN) return;
    int node = gid >> 4, k = gid & 15;

    const float4* x4 = (const float4*)(x + (size_t)node * D_FEAT);
    float acc = b_agg[k];
    #pragma unroll 8
    for (int dv = 0; dv < D_FEAT / 4; ++dv) {
        float4 xv = x4[dv];
        acc = fmaf(xv.x, Wl[(4 * dv + 0) * HIDDEN + k], acc);
        acc = fmaf(xv.y, Wl[(4 * dv + 1) * HIDDEN + k], acc);
        acc = fmaf(xv.z, Wl[(4 * dv + 2) * HIDDEN + k], acc);
        acc = fmaf(xv.w, Wl[(4 * dv + 3) * HIDDEN + k], acc);
    }
    h_agg[gid] = acc;
    agg_enc[gid] = 0u;   // < encoding of any finite float -> "no edge" sentinel
}

// Kernel 2: segment max over edges. 16 consecutive threads handle one edge
// (coalesced 64B gather of h_agg[src]). Read-check before atomicMax.
__global__ __launch_bounds__(256) void k_edge(
    const int* __restrict__ src, const int* __restrict__ dst,
    const float* __restrict__ h_agg, unsigned* __restrict__ agg_enc,
    long long total)
{
    long long tid = (long long)blockIdx.x * 256 + threadIdx.x;
    if (tid >= total) return;
    int e = (int)(tid >> 4), k = (int)(tid & 15);
    int s = src[e], d = dst[e];
    unsigned ev = enc_f32(h_agg[(size_t)s * HIDDEN + k]);
    unsigned* addr = agg_enc + (size_t)d * HIDDEN + k;
    if (ev > *addr) atomicMax(addr, ev);   // stale read only causes extra atomic, never a miss
}

// Kernel 3: h = x@W_node + b_node; neighs = agg@W_neigh + b_neigh;
// out = l2norm(concat(h, neighs)). Thread j owns output column j for M3 nodes.
__global__ __launch_bounds__(256) void k_out(
    const float* __restrict__ x, const float* __restrict__ W_node,
    const float* __restrict__ b_node, const unsigned* __restrict__ agg_enc,
    const float* __restrict__ W_neigh, const float* __restrict__ b_neigh,
    float* __restrict__ out)
{
    __shared__ float xs[M3 * D_FEAT];     // 32 KB
    __shared__ float aggs[M3 * HIDDEN];   // 2 KB
    __shared__ float red[4 * M3];         // per-wave partial sumsq

    int t = threadIdx.x;
    int base = blockIdx.x * M3;

    // Stage x tile (32 rows x 256 f32) and decoded agg tile.
    const float4* xg = (const float4*)(x + (size_t)base * D_FEAT);
    float4* xs4s = (float4*)xs;
    #pragma unroll
    for (int i = 0; i < M3 * D_FEAT / 4 / 256; ++i)
        xs4s[i * 256 + t] = xg[i * 256 + t];
    for (int i = t; i < M3 * HIDDEN; i += 256) {
        unsigned u = agg_enc[(size_t)base * HIDDEN + i];
        aggs[i] = (u == 0u) ? 0.0f : dec_f32(u);
    }
    __syncthreads();

    int j = t;  // output column 0..255
    float acc[M3];
    {
        float bn = b_node[j];
        #pragma unroll
        for (int m = 0; m < M3; ++m) acc[m] = bn;
    }

    const float4* xs4 = (const float4*)xs;
    for (int d4 = 0; d4 < D_FEAT / 4; ++d4) {
        int d = d4 * 4;
        float w0 = W_node[(d + 0) * OUT + j];
        float w1 = W_node[(d + 1) * OUT + j];
        float w2 = W_node[(d + 2) * OUT + j];
        float w3 = W_node[(d + 3) * OUT + j];
        #pragma unroll
        for (int m = 0; m < M3; ++m) {
            float4 xv = xs4[m * (D_FEAT / 4) + d4];   // LDS broadcast
            acc[m] = fmaf(xv.x, w0, acc[m]);
            acc[m] = fmaf(xv.y, w1, acc[m]);
            acc[m] = fmaf(xv.z, w2, acc[m]);
            acc[m] = fmaf(xv.w, w3, acc[m]);
        }
    }

    // neighbour layer: 16-wide dot per node
    float nv[M3];
    {
        float wn[HIDDEN];
        #pragma unroll
        for (int k = 0; k < HIDDEN; ++k) wn[k] = W_neigh[k * OUT + j];
        float bnb = b_neigh[j];
        #pragma unroll
        for (int m = 0; m < M3; ++m) {
            float a = bnb;
            #pragma unroll
            for (int k = 0; k < HIDDEN; ++k)
                a = fmaf(aggs[m * HIDDEN + k], wn[k], a);
            nv[m] = a;
        }
    }

    // block-wide sum of squares per node (over 512 = 2*256 columns)
    int wave = t >> 6, lane = t & 63;
    #pragma unroll
    for (int m = 0; m < M3; ++m) {
        float v = acc[m] * acc[m] + nv[m] * nv[m];
        v += __shfl_xor(v, 1);
        v += __shfl_xor(v, 2);
        v += __shfl_xor(v, 4);
        v += __shfl_xor(v, 8);
        v += __shfl_xor(v, 16);
        v += __shfl_xor(v, 32);
        if (lane == 0) red[wave * M3 + m] = v;
    }
    __syncthreads();

    #pragma unroll
    for (int m = 0; m < M3; ++m) {
        float sq = red[0 * M3 + m] + red[1 * M3 + m] + red[2 * M3 + m] + red[3 * M3 + m];
        float inv = rsqrtf(fmaxf(sq, 1e-12f));
        size_t row = (size_t)(base + m) * (2 * OUT);
        out[row + j] = acc[m] * inv;
        out[row + OUT + j] = nv[m] * inv;
    }
}

extern "C" void kernel_launch(void* const* d_in, const int* in_sizes, int n_in,
                              void* d_out, int out_size, void* d_ws, size_t ws_size,
                              hipStream_t stream) {
    const float* x       = (const float*)d_in[0];
    const int*   src     = (const int*)d_in[1];
    const int*   dst     = (const int*)d_in[2];
    const float* W_node  = (const float*)d_in[3];
    const float* b_node  = (const float*)d_in[4];
    const float* W_agg   = (const float*)d_in[5];
    const float* b_agg   = (const float*)d_in[6];
    const float* W_neigh = (const float*)d_in[7];
    const float* b_neigh = (const float*)d_in[8];
    float* out = (float*)d_out;

    float*    h_agg   = (float*)d_ws;
    unsigned* agg_enc = (unsigned*)((char*)d_ws + (size_t)N_NODES * HIDDEN * sizeof(float));

    int g1 = (N_NODES * HIDDEN + 255) / 256;
    k_hagg<<<g1, 256, 0, stream>>>(x, W_agg, b_agg, h_agg, agg_enc);

    long long total = (long long)N_EDGES * HIDDEN;
    int g2 = (int)((total + 255) / 256);
    k_edge<<<g2, 256, 0, stream>>>(src, dst, h_agg, agg_enc, total);

    int g3 = N_NODES / M3;   // 3125
    k_out<<<g3, 256, 0, stream>>>(x, W_node, b_node, agg_enc, W_neigh, b_neigh, out);
}

// Round 2
// 370.232 us; speedup vs baseline: 2.1898x; 2.1898x over previous
//
#include <hip/hip_runtime.h>

#define N_NODES 100000
#define N_EDGES 3200000
#define D_FEAT 256
#define HIDDEN 16
#define OUT 256

typedef __attribute__((ext_vector_type(8))) _Float16 half8;
typedef __attribute__((ext_vector_type(4))) float f32x4;

// Monotone float<->uint mapping so unsigned atomicMax == float max.
__device__ __forceinline__ unsigned enc_f32(float f) {
    unsigned u = __float_as_uint(f);
    return (u & 0x80000000u) ? ~u : (u | 0x80000000u);
}
__device__ __forceinline__ float dec_f32(unsigned u) {
    unsigned b = (u & 0x80000000u) ? (u & 0x7FFFFFFFu) : ~u;
    return __uint_as_float(b);
}

// Kernel 1: h_agg = x @ W_agg + b_agg (fp32), zero agg_enc, and emit x as f16.
__global__ __launch_bounds__(256) void k_hagg(
    const float* __restrict__ x, const float* __restrict__ W_agg,
    const float* __restrict__ b_agg, float* __restrict__ h_agg,
    unsigned* __restrict__ agg_enc, _Float16* __restrict__ xh)
{
    __shared__ float Wl[D_FEAT * HIDDEN];   // 16 KB
    int t = threadIdx.x;
    for (int i = t; i < D_FEAT * HIDDEN; i += 256) Wl[i] = W_agg[i];
    __syncthreads();

    int gid = blockIdx.x * 256 + t;
    int node = gid >> 4, k = gid & 15;

    const float4* x4 = (const float4*)(x + (size_t)node * D_FEAT);
    float acc = b_agg[k];
    #pragma unroll 8
    for (int dv = 0; dv < D_FEAT / 4; ++dv) {
        float4 xv = x4[dv];
        acc = fmaf(xv.x, Wl[(4 * dv + 0) * HIDDEN + k], acc);
        acc = fmaf(xv.y, Wl[(4 * dv + 1) * HIDDEN + k], acc);
        acc = fmaf(xv.z, Wl[(4 * dv + 2) * HIDDEN + k], acc);
        acc = fmaf(xv.w, Wl[(4 * dv + 3) * HIDDEN + k], acc);
    }
    h_agg[gid] = acc;
    agg_enc[gid] = 0u;   // < encoding of any finite float -> "no edge" sentinel

    // f16 conversion of this thread's 16-element slice of the row (L1-hot).
    const float* xr = x + (size_t)node * D_FEAT + k * 16;
    half8 lo, hi;
    #pragma unroll
    for (int i = 0; i < 8; ++i) { lo[i] = (_Float16)xr[i]; hi[i] = (_Float16)xr[8 + i]; }
    half8* xo = (half8*)(xh + (size_t)node * D_FEAT + k * 16);
    xo[0] = lo; xo[1] = hi;
}

// Kernel 2: segment max via atomicMax on encoded floats; read-check first.
__global__ __launch_bounds__(256) void k_edge(
    const int* __restrict__ src, const int* __restrict__ dst,
    const float* __restrict__ h_agg, unsigned* __restrict__ agg_enc,
    long long total)
{
    long long tid = (long long)blockIdx.x * 256 + threadIdx.x;
    if (tid >= total) return;
    int e = (int)(tid >> 4), k = (int)(tid & 15);
    int s = src[e], d = dst[e];
    unsigned ev = enc_f32(h_agg[(size_t)s * HIDDEN + k]);
    unsigned* addr = agg_enc + (size_t)d * HIDDEN + k;
    if (ev > *addr) atomicMax(addr, ev);
}

// Pack W_node / W_neigh into MFMA B-fragment layout (f16).
// Wp[((nb*8+kb)*64+l)*8+j]  = W_node[kb*32+(l>>4)*8+j][nb*16+(l&15)]
// Wnp[(nb*64+l)*8+j]        = k<16 ? W_neigh[k][nb*16+(l&15)] : 0, k=(l>>4)*8+j
__global__ void k_pack(const float* __restrict__ Wn, const float* __restrict__ Wng,
                       _Float16* __restrict__ Wp, _Float16* __restrict__ Wnp)
{
    int id = blockIdx.x * 256 + threadIdx.x;
    if (id < 16 * 8 * 64) {
        int l = id & 63, kb = (id >> 6) & 7, nb = id >> 9;
        int col = nb * 16 + (l & 15);
        int k0 = kb * 32 + (l >> 4) * 8;
        half8 v;
        #pragma unroll
        for (int j = 0; j < 8; ++j) v[j] = (_Float16)Wn[(size_t)(k0 + j) * OUT + col];
        ((half8*)Wp)[id] = v;
    } else if (id < 16 * 8 * 64 + 16 * 64) {
        int id2 = id - 16 * 8 * 64;
        int l = id2 & 63, nb = id2 >> 6;
        int col = nb * 16 + (l & 15);
        int k0 = (l >> 4) * 8;
        half8 v;
        #pragma unroll
        for (int j = 0; j < 8; ++j) {
            int k = k0 + j;
            v[j] = (k < HIDDEN) ? (_Float16)Wng[(size_t)k * OUT + col] : (_Float16)0.f;
        }
        ((half8*)Wnp)[id2] = v;
    }
}

// Decode agg_enc -> f16 [N][32], upper 16 zero (K-padding for the MFMA).
__global__ __launch_bounds__(256) void k_dec(
    const unsigned* __restrict__ enc, _Float16* __restrict__ agg32)
{
    int idx = blockIdx.x * 256 + threadIdx.x;
    if (idx >= N_NODES * 32) return;
    int node = idx >> 5, kk = idx & 31;
    float v = 0.f;
    if (kk < HIDDEN) { unsigned u = enc[node * HIDDEN + kk]; if (u) v = dec_f32(u); }
    agg32[idx] = (_Float16)v;
}

// Kernel 3: MFMA h = x@W_node, neighs = agg@W_neigh, concat + l2-normalize.
// Block: 256 thr = 4 waves; tile 64 nodes x 256 cols; wave w owns cols [w*64,w*64+64).
__global__ __launch_bounds__(256) void k_out_mfma(
    const _Float16* __restrict__ xh, const _Float16* __restrict__ Wp,
    const float* __restrict__ b_node, const _Float16* __restrict__ agg32,
    const _Float16* __restrict__ Wnp, const float* __restrict__ b_neigh,
    float* __restrict__ out)
{
    __shared__ float ss[4][64];
    __shared__ float invl[64];

    int t = threadIdx.x;
    int w = t >> 6, l = t & 63;
    int lr = l & 15, lg = l >> 4;
    int base = blockIdx.x * 64;

    f32x4 acc[4][4];
    #pragma unroll
    for (int mb = 0; mb < 4; ++mb)
        #pragma unroll
        for (int nb = 0; nb < 4; ++nb) acc[mb][nb] = (f32x4){0.f, 0.f, 0.f, 0.f};

    size_t arow[4];
    #pragma unroll
    for (int mb = 0; mb < 4; ++mb) {
        int node = base + mb * 16 + lr;
        if (node > N_NODES - 1) node = N_NODES - 1;
        arow[mb] = (size_t)node * D_FEAT + lg * 8;
    }

    const half8* WpV = (const half8*)Wp;
    #pragma unroll
    for (int kb = 0; kb < 8; ++kb) {
        half8 a[4], b[4];
        #pragma unroll
        for (int mb = 0; mb < 4; ++mb)
            a[mb] = *(const half8*)(xh + arow[mb] + kb * 32);
        #pragma unroll
        for (int nb = 0; nb < 4; ++nb)
            b[nb] = WpV[((w * 4 + nb) * 8 + kb) * 64 + l];
        #pragma unroll
        for (int mb = 0; mb < 4; ++mb)
            #pragma unroll
            for (int nb = 0; nb < 4; ++nb)
                acc[mb][nb] = __builtin_amdgcn_mfma_f32_16x16x32_f16(
                    a[mb], b[nb], acc[mb][nb], 0, 0, 0);
    }

    // neighbour layer: one MFMA per (mb,nb), K=32 (upper 16 zero-padded)
    f32x4 nacc[4][4];
    {
        half8 an[4], bn[4];
        #pragma unroll
        for (int mb = 0; mb < 4; ++mb) {
            int node = base + mb * 16 + lr;
            if (node > N_NODES - 1) node = N_NODES - 1;
            an[mb] = *(const half8*)(agg32 + (size_t)node * 32 + lg * 8);
        }
        #pragma unroll
        for (int nb = 0; nb < 4; ++nb)
            bn[nb] = ((const half8*)Wnp)[(w * 4 + nb) * 64 + l];
        f32x4 z = (f32x4){0.f, 0.f, 0.f, 0.f};
        #pragma unroll
        for (int mb = 0; mb < 4; ++mb)
            #pragma unroll
            for (int nb = 0; nb < 4; ++nb)
                nacc[mb][nb] = __builtin_amdgcn_mfma_f32_16x16x32_f16(
                    an[mb], bn[nb], z, 0, 0, 0);
    }

    // add biases (col = w*64 + nb*16 + lr)
    float bnc[4], bec[4];
    #pragma unroll
    for (int nb = 0; nb < 4; ++nb) {
        int col = w * 64 + nb * 16 + lr;
        bnc[nb] = b_node[col];
        bec[nb] = b_neigh[col];
    }
    #pragma unroll
    for (int mb = 0; mb < 4; ++mb)
        #pragma unroll
        for (int nb = 0; nb < 4; ++nb)
            #pragma unroll
            for (int r = 0; r < 4; ++r) {
                acc[mb][nb][r] += bnc[nb];
                nacc[mb][nb][r] += bec[nb];
            }

    // per-lane partial sum of squares for node slot (mb, lg, r)
    #pragma unroll
    for (int mb = 0; mb < 4; ++mb) {
        float p[4] = {0.f, 0.f, 0.f, 0.f};
        #pragma unroll
        for (int nb = 0; nb < 4; ++nb)
            #pragma unroll
            for (int r = 0; r < 4; ++r)
                p[r] += acc[mb][nb][r] * acc[mb][nb][r] + nacc[mb][nb][r] * nacc[mb][nb][r];
        #pragma unroll
        for (int r = 0; r < 4; ++r) {
            float v = p[r];
            v += __shfl_xor(v, 1);
            v += __shfl_xor(v, 2);
            v += __shfl_xor(v, 4);
            v += __shfl_xor(v, 8);
            if (lr == 0) ss[w][mb * 16 + lg * 4 + r] = v;
        }
    }
    __syncthreads();
    if (t < 64) {
        float sq = ss[0][t] + ss[1][t] + ss[2][t] + ss[3][t];
        invl[t] = rsqrtf(fmaxf(sq, 1e-12f));
    }
    __syncthreads();

    // scaled stores
    #pragma unroll
    for (int mb = 0; mb < 4; ++mb)
        #pragma unroll
        for (int r = 0; r < 4; ++r) {
            int slot = mb * 16 + lg * 4 + r;
            int node = base + slot;
            if (node < N_NODES) {
                float inv = invl[slot];
                size_t row = (size_t)node * (2 * OUT);
                #pragma unroll
                for (int nb = 0; nb < 4; ++nb) {
                    int col = w * 64 + nb * 16 + lr;
                    out[row + col] = acc[mb][nb][r] * inv;
                    out[row + OUT + col] = nacc[mb][nb][r] * inv;
                }
            }
        }
}

extern "C" void kernel_launch(void* const* d_in, const int* in_sizes, int n_in,
                              void* d_out, int out_size, void* d_ws, size_t ws_size,
                              hipStream_t stream) {
    const float* x       = (const float*)d_in[0];
    const int*   src     = (const int*)d_in[1];
    const int*   dst     = (const int*)d_in[2];
    const float* W_node  = (const float*)d_in[3];
    const float* b_node  = (const float*)d_in[4];
    const float* W_agg   = (const float*)d_in[5];
    const float* b_agg   = (const float*)d_in[6];
    const float* W_neigh = (const float*)d_in[7];
    const float* b_neigh = (const float*)d_in[8];
    float* out = (float*)d_out;

    char* ws = (char*)d_ws;
    float*     h_agg   = (float*)ws;                                    ws += (size_t)N_NODES * HIDDEN * 4;
    unsigned*  agg_enc = (unsigned*)ws;                                 ws += (size_t)N_NODES * HIDDEN * 4;
    _Float16*  xh      = (_Float16*)ws;                                 ws += (size_t)N_NODES * D_FEAT * 2;
    _Float16*  agg32   = (_Float16*)ws;                                 ws += (size_t)N_NODES * 32 * 2;
    _Float16*  Wp      = (_Float16*)ws;                                 ws += (size_t)16 * 8 * 64 * 8 * 2;
    _Float16*  Wnp     = (_Float16*)ws;

    int g1 = (N_NODES * HIDDEN) / 256;   // 6250
    k_hagg<<<g1, 256, 0, stream>>>(x, W_agg, b_agg, h_agg, agg_enc, xh);

    k_pack<<<36, 256, 0, stream>>>(W_node, W_neigh, Wp, Wnp);

    long long total = (long long)N_EDGES * HIDDEN;
    int g2 = (int)((total + 255) / 256);
    k_edge<<<g2, 256, 0, stream>>>(src, dst, h_agg, agg_enc, total);

    int g4 = (N_NODES * 32) / 256;       // 12500
    k_dec<<<g4, 256, 0, stream>>>(agg_enc, agg32);

    int g3 = (N_NODES + 63) / 64;        // 1563
    k_out_mfma<<<g3, 256, 0, stream>>>(xh, Wp, b_node, agg32, Wnp, b_neigh, out);
}

// Round 3
// 348.778 us; speedup vs baseline: 2.3245x; 1.0615x over previous
//
#include <hip/hip_runtime.h>

#define N_NODES 100000
#define N_EDGES 3200000
#define D_FEAT 256
#define HIDDEN 16
#define OUT 256

typedef __attribute__((ext_vector_type(8))) _Float16 half8;
typedef __attribute__((ext_vector_type(4))) float f32x4;

__device__ __forceinline__ unsigned umax32(unsigned a, unsigned b) { return a > b ? a : b; }

// Monotone f16-bits <-> u16 mapping: encoded compare == float compare (no NaNs here).
__device__ __forceinline__ unsigned short enc16(unsigned short u) {
    return (u & 0x8000) ? (unsigned short)~u : (unsigned short)(u | 0x8000);
}
__device__ __forceinline__ _Float16 dec16(unsigned short e) {
    // e == 0 is the "no edge" sentinel (below every finite encoding) -> 0.0
    if (e == 0) return (_Float16)0.f;
    unsigned short b = (e & 0x8000) ? (unsigned short)(e & 0x7FFF) : (unsigned short)~e;
    return __builtin_bit_cast(_Float16, b);
}

// Kernel 1: h_agg = x @ W_agg + b_agg (fp32 accum), emit:
//   hpk  [N][8] u32 : packed encoded-f16 pairs of h_agg  (gather table, 3.2 MB)
//   aenc [N][8] u32 : zero-init atomic target (same layout)
//   xh   [N][256] f16 : x cast to f16 for the MFMA kernel
__global__ __launch_bounds__(256) void k_hagg(
    const float* __restrict__ x, const float* __restrict__ W_agg,
    const float* __restrict__ b_agg, unsigned* __restrict__ hpk,
    unsigned* __restrict__ aenc, _Float16* __restrict__ xh)
{
    __shared__ float Wl[D_FEAT * HIDDEN];   // 16 KB
    int t = threadIdx.x;
    for (int i = t; i < D_FEAT * HIDDEN; i += 256) Wl[i] = W_agg[i];
    __syncthreads();

    int gid = blockIdx.x * 256 + t;
    int node = gid >> 4, k = gid & 15;

    const float4* x4 = (const float4*)(x + (size_t)node * D_FEAT);
    float acc = b_agg[k];
    #pragma unroll 8
    for (int dv = 0; dv < D_FEAT / 4; ++dv) {
        float4 xv = x4[dv];
        acc = fmaf(xv.x, Wl[(4 * dv + 0) * HIDDEN + k], acc);
        acc = fmaf(xv.y, Wl[(4 * dv + 1) * HIDDEN + k], acc);
        acc = fmaf(xv.z, Wl[(4 * dv + 2) * HIDDEN + k], acc);
        acc = fmaf(xv.w, Wl[(4 * dv + 3) * HIDDEN + k], acc);
    }

    unsigned short e16 = enc16(__builtin_bit_cast(unsigned short, (_Float16)acc));
    unsigned other = (unsigned)__shfl_xor((int)e16, 1);
    if ((k & 1) == 0) {
        unsigned word = (unsigned)e16 | (other << 16);
        size_t idx = (size_t)node * 8 + (k >> 1);
        hpk[idx] = word;
        aenc[idx] = 0u;
    }

    // f16 conversion of this thread's 16-element slice of the row (L1-hot).
    const float* xr = x + (size_t)node * D_FEAT + k * 16;
    half8 lo, hi;
    #pragma unroll
    for (int i = 0; i < 8; ++i) { lo[i] = (_Float16)xr[i]; hi[i] = (_Float16)xr[8 + i]; }
    half8* xo = (half8*)(xh + (size_t)node * D_FEAT + k * 16);
    xo[0] = lo; xo[1] = hi;
}

// Kernel 2: segment max. 8 threads/edge; each owns one packed pair.
// Stale-read check is safe: values are monotone increasing, so a stale read
// only under-estimates -> extra CAS attempt, never a wrong skip... and skips
// compare against stale <= current, so skipping is always correct.
__global__ __launch_bounds__(256) void k_edge(
    const int* __restrict__ src, const int* __restrict__ dst,
    const unsigned* __restrict__ hpk, unsigned* __restrict__ aenc)
{
    int tid = blockIdx.x * 256 + threadIdx.x;
    int e = tid >> 3, p = tid & 7;
    int s = src[e], d = dst[e];
    unsigned mine = hpk[(size_t)s * 8 + p];
    unsigned* addr = aenc + (size_t)d * 8 + p;

    unsigned cur = *addr;
    unsigned lo = umax32(cur & 0xFFFFu, mine & 0xFFFFu);
    unsigned hi = umax32(cur >> 16, mine >> 16);
    unsigned nv = lo | (hi << 16);
    while (nv != cur) {
        unsigned old = atomicCAS(addr, cur, nv);
        if (old == cur) break;
        cur = old;
        lo = umax32(cur & 0xFFFFu, mine & 0xFFFFu);
        hi = umax32(cur >> 16, mine >> 16);
        nv = lo | (hi << 16);
    }
}

// Pack W_node / W_neigh into MFMA B-fragment layout (f16).
__global__ void k_pack(const float* __restrict__ Wn, const float* __restrict__ Wng,
                       _Float16* __restrict__ Wp, _Float16* __restrict__ Wnp)
{
    int id = blockIdx.x * 256 + threadIdx.x;
    if (id < 16 * 8 * 64) {
        int l = id & 63, kb = (id >> 6) & 7, nb = id >> 9;
        int col = nb * 16 + (l & 15);
        int k0 = kb * 32 + (l >> 4) * 8;
        half8 v;
        #pragma unroll
        for (int j = 0; j < 8; ++j) v[j] = (_Float16)Wn[(size_t)(k0 + j) * OUT + col];
        ((half8*)Wp)[id] = v;
    } else if (id < 16 * 8 * 64 + 16 * 64) {
        int id2 = id - 16 * 8 * 64;
        int l = id2 & 63, nb = id2 >> 6;
        int col = nb * 16 + (l & 15);
        int k0 = (l >> 4) * 8;
        half8 v;
        #pragma unroll
        for (int j = 0; j < 8; ++j) {
            int k = k0 + j;
            v[j] = (k < HIDDEN) ? (_Float16)Wng[(size_t)k * OUT + col] : (_Float16)0.f;
        }
        ((half8*)Wnp)[id2] = v;
    }
}

// Kernel 3: MFMA h = x@W_node, neighs = agg@W_neigh, concat + l2-normalize.
// Decodes packed agg directly into LDS (no k_dec kernel).
__global__ __launch_bounds__(256) void k_out_mfma(
    const _Float16* __restrict__ xh, const _Float16* __restrict__ Wp,
    const float* __restrict__ b_node, const unsigned* __restrict__ aenc,
    const _Float16* __restrict__ Wnp, const float* __restrict__ b_neigh,
    float* __restrict__ out)
{
    __shared__ _Float16 aggL[64][40];  // padded: rows start 80B apart (bank-spread)
    __shared__ float ss[4][64];
    __shared__ float invl[64];

    int t = threadIdx.x;
    int w = t >> 6, l = t & 63;
    int lr = l & 15, lg = l >> 4;
    int base = blockIdx.x * 64;

    // Stage + decode agg tile: [64 nodes][16 vals], zero-pad cols 16..31.
    for (int i = t; i < 64 * 8; i += 256) {
        int nl = i >> 3, p = i & 7;
        int gn = base + nl;
        unsigned v = (gn < N_NODES) ? aenc[(size_t)gn * 8 + p] : 0u;
        aggL[nl][2 * p]     = dec16((unsigned short)(v & 0xFFFFu));
        aggL[nl][2 * p + 1] = dec16((unsigned short)(v >> 16));
    }
    for (int i = t; i < 64 * 16; i += 256)
        aggL[i >> 4][16 + (i & 15)] = (_Float16)0.f;
    __syncthreads();

    f32x4 acc[4][4];
    #pragma unroll
    for (int mb = 0; mb < 4; ++mb)
        #pragma unroll
        for (int nb = 0; nb < 4; ++nb) acc[mb][nb] = (f32x4){0.f, 0.f, 0.f, 0.f};

    size_t arow[4];
    #pragma unroll
    for (int mb = 0; mb < 4; ++mb) {
        int node = base + mb * 16 + lr;
        if (node > N_NODES - 1) node = N_NODES - 1;
        arow[mb] = (size_t)node * D_FEAT + lg * 8;
    }

    const half8* WpV = (const half8*)Wp;
    #pragma unroll
    for (int kb = 0; kb < 8; ++kb) {
        half8 a[4], b[4];
        #pragma unroll
        for (int mb = 0; mb < 4; ++mb)
            a[mb] = *(const half8*)(xh + arow[mb] + kb * 32);
        #pragma unroll
        for (int nb = 0; nb < 4; ++nb)
            b[nb] = WpV[((w * 4 + nb) * 8 + kb) * 64 + l];
        #pragma unroll
        for (int mb = 0; mb < 4; ++mb)
            #pragma unroll
            for (int nb = 0; nb < 4; ++nb)
                acc[mb][nb] = __builtin_amdgcn_mfma_f32_16x16x32_f16(
                    a[mb], b[nb], acc[mb][nb], 0, 0, 0);
    }

    // neighbour layer: one MFMA per (mb,nb), K=32 (upper 16 zero-padded)
    f32x4 nacc[4][4];
    {
        half8 an[4], bn[4];
        #pragma unroll
        for (int mb = 0; mb < 4; ++mb)
            an[mb] = *(const half8*)(&aggL[mb * 16 + lr][lg * 8]);
        #pragma unroll
        for (int nb = 0; nb < 4; ++nb)
            bn[nb] = ((const half8*)Wnp)[(w * 4 + nb) * 64 + l];
        f32x4 z = (f32x4){0.f, 0.f, 0.f, 0.f};
        #pragma unroll
        for (int mb = 0; mb < 4; ++mb)
            #pragma unroll
            for (int nb = 0; nb < 4; ++nb)
                nacc[mb][nb] = __builtin_amdgcn_mfma_f32_16x16x32_f16(
                    an[mb], bn[nb], z, 0, 0, 0);
    }

    float bnc[4], bec[4];
    #pragma unroll
    for (int nb = 0; nb < 4; ++nb) {
        int col = w * 64 + nb * 16 + lr;
        bnc[nb] = b_node[col];
        bec[nb] = b_neigh[col];
    }
    #pragma unroll
    for (int mb = 0; mb < 4; ++mb)
        #pragma unroll
        for (int nb = 0; nb < 4; ++nb)
            #pragma unroll
            for (int r = 0; r < 4; ++r) {
                acc[mb][nb][r] += bnc[nb];
                nacc[mb][nb][r] += bec[nb];
            }

    int wave = w;
    #pragma unroll
    for (int mb = 0; mb < 4; ++mb) {
        float p[4] = {0.f, 0.f, 0.f, 0.f};
        #pragma unroll
        for (int nb = 0; nb < 4; ++nb)
            #pragma unroll
            for (int r = 0; r < 4; ++r)
                p[r] += acc[mb][nb][r] * acc[mb][nb][r] + nacc[mb][nb][r] * nacc[mb][nb][r];
        #pragma unroll
        for (int r = 0; r < 4; ++r) {
            float v = p[r];
            v += __shfl_xor(v, 1);
            v += __shfl_xor(v, 2);
            v += __shfl_xor(v, 4);
            v += __shfl_xor(v, 8);
            if (lr == 0) ss[wave][mb * 16 + lg * 4 + r] = v;
        }
    }
    __syncthreads();
    if (t < 64) {
        float sq = ss[0][t] + ss[1][t] + ss[2][t] + ss[3][t];
        invl[t] = rsqrtf(fmaxf(sq, 1e-12f));
    }
    __syncthreads();

    #pragma unroll
    for (int mb = 0; mb < 4; ++mb)
        #pragma unroll
        for (int r = 0; r < 4; ++r) {
            int slot = mb * 16 + lg * 4 + r;
            int node = base + slot;
            if (node < N_NODES) {
                float inv = invl[slot];
                size_t row = (size_t)node * (2 * OUT);
                #pragma unroll
                for (int nb = 0; nb < 4; ++nb) {
                    int col = w * 64 + nb * 16 + lr;
                    out[row + col] = acc[mb][nb][r] * inv;
                    out[row + OUT + col] = nacc[mb][nb][r] * inv;
                }
            }
        }
}

extern "C" void kernel_launch(void* const* d_in, const int* in_sizes, int n_in,
                              void* d_out, int out_size, void* d_ws, size_t ws_size,
                              hipStream_t stream) {
    const float* x       = (const float*)d_in[0];
    const int*   src     = (const int*)d_in[1];
    const int*   dst     = (const int*)d_in[2];
    const float* W_node  = (const float*)d_in[3];
    const float* b_node  = (const float*)d_in[4];
    const float* W_agg   = (const float*)d_in[5];
    const float* b_agg   = (const float*)d_in[6];
    const float* W_neigh = (const float*)d_in[7];
    const float* b_neigh = (const float*)d_in[8];
    float* out = (float*)d_out;

    char* ws = (char*)d_ws;
    unsigned*  hpk  = (unsigned*)ws;      ws += (size_t)N_NODES * 8 * 4;
    unsigned*  aenc = (unsigned*)ws;      ws += (size_t)N_NODES * 8 * 4;
    _Float16*  xh   = (_Float16*)ws;      ws += (size_t)N_NODES * D_FEAT * 2;
    _Float16*  Wp   = (_Float16*)ws;      ws += (size_t)16 * 8 * 64 * 8 * 2;
    _Float16*  Wnp  = (_Float16*)ws;

    int g1 = (N_NODES * HIDDEN) / 256;   // 6250
    k_hagg<<<g1, 256, 0, stream>>>(x, W_agg, b_agg, hpk, aenc, xh);

    k_pack<<<36, 256, 0, stream>>>(W_node, W_neigh, Wp, Wnp);

    int g2 = (N_EDGES * 8) / 256;        // 100000
    k_edge<<<g2, 256, 0, stream>>>(src, dst, hpk, aenc);

    int g3 = (N_NODES + 63) / 64;        // 1563
    k_out_mfma<<<g3, 256, 0, stream>>>(xh, Wp, b_node, aenc, Wnp, b_neigh, out);
}

// Round 4
// 348.111 us; speedup vs baseline: 2.3289x; 1.0019x over previous
//
#include <hip/hip_runtime.h>

#define N_NODES 100000
#define N_EDGES 3200000
#define D_FEAT 256
#define HIDDEN 16
#define OUT 256

typedef __attribute__((ext_vector_type(8))) _Float16 half8;
typedef __attribute__((ext_vector_type(4))) float f32x4;

__device__ __forceinline__ unsigned umax32(unsigned a, unsigned b) { return a > b ? a : b; }

// Monotone f16-bits <-> u16 mapping: encoded compare == float compare (no NaNs here).
__device__ __forceinline__ unsigned short enc16(unsigned short u) {
    return (u & 0x8000) ? (unsigned short)~u : (unsigned short)(u | 0x8000);
}
__device__ __forceinline__ _Float16 dec16(unsigned short e) {
    // e == 0 is the "no edge" sentinel (below every finite encoding) -> 0.0
    if (e == 0) return (_Float16)0.f;
    unsigned short b = (e & 0x8000) ? (unsigned short)(e & 0x7FFF) : (unsigned short)~e;
    return __builtin_bit_cast(_Float16, b);
}

// Kernel 1: h_agg = x @ W_agg + b_agg (fp32 accum), emit packed-encoded h_agg
// (hpk), zeroed atomic table (aenc), and x cast to f16 (xh).
// W_agg transposed in LDS with +4 pad: one ds_read_b128 per 4-FMA iter.
__global__ __launch_bounds__(256) void k_hagg(
    const float* __restrict__ x, const float* __restrict__ W_agg,
    const float* __restrict__ b_agg, unsigned* __restrict__ hpk,
    unsigned* __restrict__ aenc, _Float16* __restrict__ xh)
{
    __shared__ float WlT[HIDDEN * 260];   // [k][d], row stride 260 (1040B, 16B-aligned)
    int t = threadIdx.x;
    for (int i = t; i < D_FEAT * HIDDEN; i += 256)
        WlT[(i & 15) * 260 + (i >> 4)] = W_agg[i];
    __syncthreads();

    int gid = blockIdx.x * 256 + t;
    int node = gid >> 4, k = gid & 15;

    const float4* x4 = (const float4*)(x + (size_t)node * D_FEAT);
    const float4* wt4 = (const float4*)(WlT + k * 260);
    float acc = b_agg[k];
    #pragma unroll 8
    for (int dv = 0; dv < D_FEAT / 4; ++dv) {
        float4 xv = x4[dv];
        float4 wv = wt4[dv];
        acc = fmaf(xv.x, wv.x, acc);
        acc = fmaf(xv.y, wv.y, acc);
        acc = fmaf(xv.z, wv.z, acc);
        acc = fmaf(xv.w, wv.w, acc);
    }

    unsigned short e16 = enc16(__builtin_bit_cast(unsigned short, (_Float16)acc));
    unsigned other = (unsigned)__shfl_xor((int)e16, 1);
    if ((k & 1) == 0) {
        unsigned word = (unsigned)e16 | (other << 16);
        size_t idx = (size_t)node * 8 + (k >> 1);
        hpk[idx] = word;
        aenc[idx] = 0u;
    }

    // f16 conversion of this thread's 16-element slice of the row (L1-hot).
    const float4* xr4 = x4 + k * 4;
    float4 c0 = xr4[0], c1 = xr4[1], c2 = xr4[2], c3 = xr4[3];
    half8 lo, hi;
    lo[0]=(_Float16)c0.x; lo[1]=(_Float16)c0.y; lo[2]=(_Float16)c0.z; lo[3]=(_Float16)c0.w;
    lo[4]=(_Float16)c1.x; lo[5]=(_Float16)c1.y; lo[6]=(_Float16)c1.z; lo[7]=(_Float16)c1.w;
    hi[0]=(_Float16)c2.x; hi[1]=(_Float16)c2.y; hi[2]=(_Float16)c2.z; hi[3]=(_Float16)c2.w;
    hi[4]=(_Float16)c3.x; hi[5]=(_Float16)c3.y; hi[6]=(_Float16)c3.z; hi[7]=(_Float16)c3.w;
    half8* xo = (half8*)(xh + (size_t)node * D_FEAT + k * 16);
    xo[0] = lo; xo[1] = hi;
}

// Kernel 2: segment max. 8 threads/edge; packed pair per lane; pre-check + CAS.
// (At its structural floor per R3 analysis — unchanged.)
__global__ __launch_bounds__(256) void k_edge(
    const int* __restrict__ src, const int* __restrict__ dst,
    const unsigned* __restrict__ hpk, unsigned* __restrict__ aenc)
{
    int tid = blockIdx.x * 256 + threadIdx.x;
    int e = tid >> 3, p = tid & 7;
    int s = src[e], d = dst[e];
    unsigned mine = hpk[(size_t)s * 8 + p];
    unsigned* addr = aenc + (size_t)d * 8 + p;

    unsigned cur = *addr;
    unsigned lo = umax32(cur & 0xFFFFu, mine & 0xFFFFu);
    unsigned hi = umax32(cur >> 16, mine >> 16);
    unsigned nv = lo | (hi << 16);
    while (nv != cur) {
        unsigned old = atomicCAS(addr, cur, nv);
        if (old == cur) break;
        cur = old;
        lo = umax32(cur & 0xFFFFu, mine & 0xFFFFu);
        hi = umax32(cur >> 16, mine >> 16);
        nv = lo | (hi << 16);
    }
}

// Pack W_node / W_neigh into MFMA B-fragment layout (f16).
__global__ void k_pack(const float* __restrict__ Wn, const float* __restrict__ Wng,
                       _Float16* __restrict__ Wp, _Float16* __restrict__ Wnp)
{
    int id = blockIdx.x * 256 + threadIdx.x;
    if (id < 16 * 8 * 64) {
        int l = id & 63, kb = (id >> 6) & 7, nb = id >> 9;
        int col = nb * 16 + (l & 15);
        int k0 = kb * 32 + (l >> 4) * 8;
        half8 v;
        #pragma unroll
        for (int j = 0; j < 8; ++j) v[j] = (_Float16)Wn[(size_t)(k0 + j) * OUT + col];
        ((half8*)Wp)[id] = v;
    } else if (id < 16 * 8 * 64 + 16 * 64) {
        int id2 = id - 16 * 8 * 64;
        int l = id2 & 63, nb = id2 >> 6;
        int col = nb * 16 + (l & 15);
        int k0 = (l >> 4) * 8;
        half8 v;
        #pragma unroll
        for (int j = 0; j < 8; ++j) {
            int k = k0 + j;
            v[j] = (k < HIDDEN) ? (_Float16)Wng[(size_t)k * OUT + col] : (_Float16)0.f;
        }
        ((half8*)Wnp)[id2] = v;
    }
}

// Kernel 3: MFMA h = x@W_node, neighs = agg@W_neigh, concat + l2-normalize.
// Explicit 2-stage register double-buffer on the kb loop (issue-early loads).
__global__ __launch_bounds__(256) void k_out_mfma(
    const _Float16* __restrict__ xh, const _Float16* __restrict__ Wp,
    const float* __restrict__ b_node, const unsigned* __restrict__ aenc,
    const _Float16* __restrict__ Wnp, const float* __restrict__ b_neigh,
    float* __restrict__ out)
{
    __shared__ _Float16 aggL[64][40];  // padded rows (80B apart)
    __shared__ float ss[4][64];
    __shared__ float invl[64];

    int t = threadIdx.x;
    int w = t >> 6, l = t & 63;
    int lr = l & 15, lg = l >> 4;
    int base = blockIdx.x * 64;

    // Stage + decode agg tile: [64 nodes][16 vals], zero-pad cols 16..31.
    for (int i = t; i < 64 * 8; i += 256) {
        int nl = i >> 3, p = i & 7;
        int gn = base + nl;
        unsigned v = (gn < N_NODES) ? aenc[(size_t)gn * 8 + p] : 0u;
        aggL[nl][2 * p]     = dec16((unsigned short)(v & 0xFFFFu));
        aggL[nl][2 * p + 1] = dec16((unsigned short)(v >> 16));
    }
    for (int i = t; i < 64 * 16; i += 256)
        aggL[i >> 4][16 + (i & 15)] = (_Float16)0.f;
    __syncthreads();

    f32x4 acc[4][4];
    #pragma unroll
    for (int mb = 0; mb < 4; ++mb)
        #pragma unroll
        for (int nb = 0; nb < 4; ++nb) acc[mb][nb] = (f32x4){0.f, 0.f, 0.f, 0.f};

    size_t arow[4];
    #pragma unroll
    for (int mb = 0; mb < 4; ++mb) {
        int node = base + mb * 16 + lr;
        if (node > N_NODES - 1) node = N_NODES - 1;
        arow[mb] = (size_t)node * D_FEAT + lg * 8;
    }

    const half8* WpV = (const half8*)Wp;
    half8 abuf[2][4], bbuf[2][4];
    #pragma unroll
    for (int mb = 0; mb < 4; ++mb)
        abuf[0][mb] = *(const half8*)(xh + arow[mb]);
    #pragma unroll
    for (int nb = 0; nb < 4; ++nb)
        bbuf[0][nb] = WpV[((w * 4 + nb) * 8 + 0) * 64 + l];

    #pragma unroll
    for (int kb = 0; kb < 8; ++kb) {
        const int cur = kb & 1, nxt = cur ^ 1;
        if (kb < 7) {
            #pragma unroll
            for (int mb = 0; mb < 4; ++mb)
                abuf[nxt][mb] = *(const half8*)(xh + arow[mb] + (kb + 1) * 32);
            #pragma unroll
            for (int nb = 0; nb < 4; ++nb)
                bbuf[nxt][nb] = WpV[((w * 4 + nb) * 8 + (kb + 1)) * 64 + l];
        }
        #pragma unroll
        for (int mb = 0; mb < 4; ++mb)
            #pragma unroll
            for (int nb = 0; nb < 4; ++nb)
                acc[mb][nb] = __builtin_amdgcn_mfma_f32_16x16x32_f16(
                    abuf[cur][mb], bbuf[cur][nb], acc[mb][nb], 0, 0, 0);
    }

    // neighbour layer: one MFMA per (mb,nb), K=32 (upper 16 zero-padded)
    f32x4 nacc[4][4];
    {
        half8 an[4], bn[4];
        #pragma unroll
        for (int mb = 0; mb < 4; ++mb)
            an[mb] = *(const half8*)(&aggL[mb * 16 + lr][lg * 8]);
        #pragma unroll
        for (int nb = 0; nb < 4; ++nb)
            bn[nb] = ((const half8*)Wnp)[(w * 4 + nb) * 64 + l];
        f32x4 z = (f32x4){0.f, 0.f, 0.f, 0.f};
        #pragma unroll
        for (int mb = 0; mb < 4; ++mb)
            #pragma unroll
            for (int nb = 0; nb < 4; ++nb)
                nacc[mb][nb] = __builtin_amdgcn_mfma_f32_16x16x32_f16(
                    an[mb], bn[nb], z, 0, 0, 0);
    }

    float bnc[4], bec[4];
    #pragma unroll
    for (int nb = 0; nb < 4; ++nb) {
        int col = w * 64 + nb * 16 + lr;
        bnc[nb] = b_node[col];
        bec[nb] = b_neigh[col];
    }
    #pragma unroll
    for (int mb = 0; mb < 4; ++mb)
        #pragma unroll
        for (int nb = 0; nb < 4; ++nb)
            #pragma unroll
            for (int r = 0; r < 4; ++r) {
                acc[mb][nb][r] += bnc[nb];
                nacc[mb][nb][r] += bec[nb];
            }

    #pragma unroll
    for (int mb = 0; mb < 4; ++mb) {
        float p[4] = {0.f, 0.f, 0.f, 0.f};
        #pragma unroll
        for (int nb = 0; nb < 4; ++nb)
            #pragma unroll
            for (int r = 0; r < 4; ++r)
                p[r] += acc[mb][nb][r] * acc[mb][nb][r] + nacc[mb][nb][r] * nacc[mb][nb][r];
        #pragma unroll
        for (int r = 0; r < 4; ++r) {
            float v = p[r];
            v += __shfl_xor(v, 1);
            v += __shfl_xor(v, 2);
            v += __shfl_xor(v, 4);
            v += __shfl_xor(v, 8);
            if (lr == 0) ss[w][mb * 16 + lg * 4 + r] = v;
        }
    }
    __syncthreads();
    if (t < 64) {
        float sq = ss[0][t] + ss[1][t] + ss[2][t] + ss[3][t];
        invl[t] = rsqrtf(fmaxf(sq, 1e-12f));
    }
    __syncthreads();

    #pragma unroll
    for (int mb = 0; mb < 4; ++mb)
        #pragma unroll
        for (int r = 0; r < 4; ++r) {
            int slot = mb * 16 + lg * 4 + r;
            int node = base + slot;
            if (node < N_NODES) {
                float inv = invl[slot];
                size_t row = (size_t)node * (2 * OUT);
                #pragma unroll
                for (int nb = 0; nb < 4; ++nb) {
                    int col = w * 64 + nb * 16 + lr;
                    out[row + col] = acc[mb][nb][r] * inv;
                    out[row + OUT + col] = nacc[mb][nb][r] * inv;
                }
            }
        }
}

extern "C" void kernel_launch(void* const* d_in, const int* in_sizes, int n_in,
                              void* d_out, int out_size, void* d_ws, size_t ws_size,
                              hipStream_t stream) {
    const float* x       = (const float*)d_in[0];
    const int*   src     = (const int*)d_in[1];
    const int*   dst     = (const int*)d_in[2];
    const float* W_node  = (const float*)d_in[3];
    const float* b_node  = (const float*)d_in[4];
    const float* W_agg   = (const float*)d_in[5];
    const float* b_agg   = (const float*)d_in[6];
    const float* W_neigh = (const float*)d_in[7];
    const float* b_neigh = (const float*)d_in[8];
    float* out = (float*)d_out;

    char* ws = (char*)d_ws;
    unsigned*  hpk  = (unsigned*)ws;      ws += (size_t)N_NODES * 8 * 4;
    unsigned*  aenc = (unsigned*)ws;      ws += (size_t)N_NODES * 8 * 4;
    _Float16*  xh   = (_Float16*)ws;      ws += (size_t)N_NODES * D_FEAT * 2;
    _Float16*  Wp   = (_Float16*)ws;      ws += (size_t)16 * 8 * 64 * 8 * 2;
    _Float16*  Wnp  = (_Float16*)ws;

    int g1 = (N_NODES * HIDDEN) / 256;   // 6250
    k_hagg<<<g1, 256, 0, stream>>>(x, W_agg, b_agg, hpk, aenc, xh);

    k_pack<<<36, 256, 0, stream>>>(W_node, W_neigh, Wp, Wnp);

    int g2 = (N_EDGES * 8) / 256;        // 100000
    k_edge<<<g2, 256, 0, stream>>>(src, dst, hpk, aenc);

    int g3 = (N_NODES + 63) / 64;        // 1563
    k_out_mfma<<<g3, 256, 0, stream>>>(xh, Wp, b_node, aenc, Wnp, b_neigh, out);
}